// Round 1
// baseline (1361.779 us; speedup 1.0000x reference)
//
#include <hip/hip_runtime.h>
#include <hip/hip_bf16.h>
#include <cstdint>

#define DIM 32
#define OUTD 128

// ---------------- index-load helper (int32 vs int64 inputs) ----------------
__device__ __forceinline__ int load_idx(const void* p, long long i, int is64) {
    if (is64) return (int)((const long long*)p)[i];
    return ((const int*)p)[i];
}

// Detect whether integer inputs are int64 (8B) or int32 (4B).
// Reads first 256 entries as int64; if most are valid node ids -> int64.
__global__ void detect_dtype_kernel(const void* __restrict__ edge, int* __restrict__ flag, int n_nodes) {
    __shared__ int cnt;
    if (threadIdx.x == 0) cnt = 0;
    __syncthreads();
    long long v = ((const long long*)edge)[threadIdx.x];
    int ok = (v >= 0 && v < (long long)n_nodes) ? 1 : 0;
    atomicAdd(&cnt, ok);
    __syncthreads();
    if (threadIdx.x == 0) *flag = (cnt > 128) ? 1 : 0;
}

__global__ void zero_int_kernel(int* __restrict__ p, int n) {
    int i = blockIdx.x * blockDim.x + threadIdx.x;
    if (i < n) p[i] = 0;
}

// count in-degree (excluding the analytic self-loop): cnt[col[e]]++
__global__ void count_kernel(const void* __restrict__ edge, const int* __restrict__ flag,
                             int* __restrict__ cnt, int e_total) {
    int i = blockIdx.x * blockDim.x + threadIdx.x;
    if (i >= e_total) return;
    int f = *flag;
    int c = load_idx(edge, (long long)e_total + i, f);
    atomicAdd(&cnt[c], 1);
}

// single-block exclusive scan of cnt -> rowptr (+ fillpos copy, dinv = rsqrt(cnt+1))
__global__ void scan_kernel(const int* __restrict__ cnt, int* __restrict__ rowptr,
                            int* __restrict__ fillpos, float* __restrict__ dinv, int n) {
    __shared__ int part[1024];
    int t = threadIdx.x;
    int chunk = (n + 1023) >> 10;
    int s = t * chunk;
    int e = min(s + chunk, n);
    int sum = 0;
    for (int i = s; i < e; ++i) sum += cnt[i];
    part[t] = sum;
    __syncthreads();
    for (int off = 1; off < 1024; off <<= 1) {
        int v = (t >= off) ? part[t - off] : 0;
        __syncthreads();
        part[t] += v;
        __syncthreads();
    }
    int run = part[t] - sum;  // exclusive prefix of this thread's chunk
    for (int i = s; i < e; ++i) {
        rowptr[i] = run;
        fillpos[i] = run;
        dinv[i] = rsqrtf((float)(cnt[i] + 1));
        run += cnt[i];
    }
    if (t == 1023) rowptr[n] = run;
}

// scatter edges into CSR (grouped by destination col), weight = dinv[row]*dinv[col]
__global__ void fill_kernel(const void* __restrict__ edge, const int* __restrict__ flag,
                            const float* __restrict__ dinv, int* __restrict__ fillpos,
                            int* __restrict__ src, float* __restrict__ w, int e_total) {
    int i = blockIdx.x * blockDim.x + threadIdx.x;
    if (i >= e_total) return;
    int f = *flag;
    int r = load_idx(edge, i, f);
    int c = load_idx(edge, (long long)e_total + i, f);
    int p = atomicAdd(&fillpos[c], 1);
    src[p] = r;
    w[p] = dinv[r] * dinv[c];
}

// out[N,32] = in[N,32] @ W[32,32]
__global__ __launch_bounds__(256) void gemm32_kernel(const float* __restrict__ in,
                                                     const float* __restrict__ W,
                                                     float* __restrict__ out, int n) {
    __shared__ float sW[32 * 32];
    __shared__ float sIn[64 * 33];
    int t = threadIdx.x;
    for (int i = t; i < 1024; i += 256) sW[i] = W[i];
    int base = blockIdx.x * 64;
    int nn = min(64, n - base);
    for (int i = t; i < nn * 32; i += 256) {
        int node = i >> 5, j = i & 31;
        sIn[node * 33 + j] = in[(size_t)(base + node) * 32 + j];
    }
    __syncthreads();
    int node = t & 63;
    int k0 = (t >> 6) * 8;
    if (node < nn) {
        float acc[8] = {0, 0, 0, 0, 0, 0, 0, 0};
        #pragma unroll
        for (int j = 0; j < 32; ++j) {
            float a = sIn[node * 33 + j];
            #pragma unroll
            for (int kk = 0; kk < 8; ++kk) acc[kk] = fmaf(a, sW[j * 32 + k0 + kk], acc[kk]);
        }
        float* op = out + (size_t)(base + node) * 32 + k0;
        *(float4*)op = make_float4(acc[0], acc[1], acc[2], acc[3]);
        *(float4*)(op + 4) = make_float4(acc[4], acc[5], acc[6], acc[7]);
    }
}

// out[c] = relu( sum_{e in CSR[c]} w_e * hw[src_e] + dinv[c]^2 * hw[c] + bias (+ res[c]) )
template <int HAS_RES>
__global__ __launch_bounds__(256) void agg_kernel(const float* __restrict__ hw,
                                                  const int* __restrict__ rowptr,
                                                  const int* __restrict__ src,
                                                  const float* __restrict__ w,
                                                  const float* __restrict__ dinv,
                                                  const float* __restrict__ bias,
                                                  const float* __restrict__ res,
                                                  float* __restrict__ out, int n) {
    int g = blockIdx.x * 8 + (threadIdx.x >> 5);
    int k = threadIdx.x & 31;
    if (g >= n) return;
    float di = dinv[g];
    float acc = di * di * hw[(size_t)g * 32 + k];
    int s = rowptr[g], e = rowptr[g + 1];
    int p = s;
    for (; p + 1 < e; p += 2) {
        int sr0 = src[p];
        int sr1 = src[p + 1];
        float w0 = w[p];
        float w1 = w[p + 1];
        float v0 = hw[(size_t)sr0 * 32 + k];
        float v1 = hw[(size_t)sr1 * 32 + k];
        acc = fmaf(w0, v0, acc);
        acc = fmaf(w1, v1, acc);
    }
    if (p < e) {
        int sr = src[p];
        acc = fmaf(w[p], hw[(size_t)sr * 32 + k], acc);
    }
    acc += bias[k];
    if (HAS_RES) acc += res[(size_t)g * 32 + k];
    out[(size_t)g * 32 + k] = fmaxf(acc, 0.0f);
}

// one block per graph: mean-pool (batch is sorted -> binary search range) + 32->128 FC
__global__ __launch_bounds__(128) void pool_fc_kernel(const float* __restrict__ h,
                                                      const void* __restrict__ batch,
                                                      const int* __restrict__ flag,
                                                      const float* __restrict__ Wl,
                                                      const float* __restrict__ bl,
                                                      float* __restrict__ out, int n) {
    __shared__ float red[4][32];
    __shared__ float sp[32];
    __shared__ int srange[2];
    int g = blockIdx.x;
    int t = threadIdx.x;
    int f = *flag;
    if (t < 2) {
        int target = g + t;
        int lo = 0, hi = n;
        while (lo < hi) {
            int mid = (lo + hi) >> 1;
            int v = load_idx(batch, mid, f);
            if (v < target) lo = mid + 1; else hi = mid;
        }
        srange[t] = lo;
    }
    __syncthreads();
    int s = srange[0], e = srange[1];
    int gi = t >> 5, k = t & 31;
    float acc = 0.f;
    for (int i = s + gi; i < e; i += 4) acc += h[(size_t)i * 32 + k];
    red[gi][k] = acc;
    __syncthreads();
    if (gi == 0) {
        float v = red[0][k] + red[1][k] + red[2][k] + red[3][k];
        sp[k] = v / fmaxf((float)(e - s), 1.0f);
    }
    __syncthreads();
    float val = bl[t];
    #pragma unroll
    for (int j = 0; j < 32; ++j) val = fmaf(sp[j], Wl[j * 128 + t], val);
    out[(size_t)g * 128 + t] = val;
}

extern "C" void kernel_launch(void* const* d_in, const int* in_sizes, int n_in,
                              void* d_out, int out_size, void* d_ws, size_t ws_size,
                              hipStream_t stream) {
    const float* x = (const float*)d_in[0];
    const void* edge = d_in[1];
    const void* batch = d_in[2];
    const float* W[6] = {(const float*)d_in[3], (const float*)d_in[5],
                         (const float*)d_in[7], (const float*)d_in[9],
                         (const float*)d_in[11], (const float*)d_in[13]};
    const float* B[6] = {(const float*)d_in[4], (const float*)d_in[6],
                         (const float*)d_in[8], (const float*)d_in[10],
                         (const float*)d_in[12], (const float*)d_in[14]};
    const float* Wl = (const float*)d_in[15];
    const float* bl = (const float*)d_in[16];
    float* out = (float*)d_out;

    int n = in_sizes[0] / DIM;      // 100000 nodes
    int eN = in_sizes[1] / 2;       // 3200000 edges
    int gN = out_size / OUTD;       // 8192 graphs

    char* ws = (char*)d_ws;
    size_t off = 0;
    auto alloc = [&](size_t bytes) {
        void* p = ws + off;
        off += (bytes + 255) & ~(size_t)255;
        return p;
    };
    int* flag    = (int*)alloc(4);
    int* cnt     = (int*)alloc((size_t)n * 4);
    int* rowptr  = (int*)alloc((size_t)(n + 1) * 4);
    int* fillpos = (int*)alloc((size_t)n * 4);
    float* dinv  = (float*)alloc((size_t)n * 4);
    int* csr_src = (int*)alloc((size_t)eN * 4);
    float* csr_w = (float*)alloc((size_t)eN * 4);
    float* bufA  = (float*)alloc((size_t)n * DIM * 4);
    float* bufB  = (float*)alloc((size_t)n * DIM * 4);
    float* bufC  = (float*)alloc((size_t)n * DIM * 4);

    detect_dtype_kernel<<<1, 256, 0, stream>>>(edge, flag, n);
    zero_int_kernel<<<(n + 255) / 256, 256, 0, stream>>>(cnt, n);
    count_kernel<<<(eN + 255) / 256, 256, 0, stream>>>(edge, flag, cnt, eN);
    scan_kernel<<<1, 1024, 0, stream>>>(cnt, rowptr, fillpos, dinv, n);
    fill_kernel<<<(eN + 255) / 256, 256, 0, stream>>>(edge, flag, dinv, fillpos, csr_src, csr_w, eN);

    int gb = (n + 63) / 64;
    int ab = (n + 7) / 8;

    // Res-block 1 (residual = x)
    gemm32_kernel<<<gb, 256, 0, stream>>>(x, W[0], bufC, n);
    agg_kernel<0><<<ab, 256, 0, stream>>>(bufC, rowptr, csr_src, csr_w, dinv, B[0], nullptr, bufA, n);
    gemm32_kernel<<<gb, 256, 0, stream>>>(bufA, W[1], bufC, n);
    agg_kernel<1><<<ab, 256, 0, stream>>>(bufC, rowptr, csr_src, csr_w, dinv, B[1], x, bufB, n);
    // Res-block 2 (residual = bufB)
    gemm32_kernel<<<gb, 256, 0, stream>>>(bufB, W[2], bufC, n);
    agg_kernel<0><<<ab, 256, 0, stream>>>(bufC, rowptr, csr_src, csr_w, dinv, B[2], nullptr, bufA, n);
    gemm32_kernel<<<gb, 256, 0, stream>>>(bufA, W[3], bufC, n);
    agg_kernel<1><<<ab, 256, 0, stream>>>(bufC, rowptr, csr_src, csr_w, dinv, B[3], bufB, bufA, n);
    // Res-block 3 (residual = bufA)
    gemm32_kernel<<<gb, 256, 0, stream>>>(bufA, W[4], bufC, n);
    agg_kernel<0><<<ab, 256, 0, stream>>>(bufC, rowptr, csr_src, csr_w, dinv, B[4], nullptr, bufB, n);
    gemm32_kernel<<<gb, 256, 0, stream>>>(bufB, W[5], bufC, n);
    agg_kernel<1><<<ab, 256, 0, stream>>>(bufC, rowptr, csr_src, csr_w, dinv, B[5], bufA, bufB, n);

    pool_fc_kernel<<<gN, 128, 0, stream>>>(bufB, batch, flag, Wl, bl, out, n);
}

// Round 2
// 909.179 us; speedup vs baseline: 1.4978x; 1.4978x over previous
//
#include <hip/hip_runtime.h>
#include <hip/hip_bf16.h>
#include <cstdint>

#define DIM 32
#define OUTD 128
#define SCAN_BS 512

// ---------------- index-load helper (int32 vs int64 inputs) ----------------
__device__ __forceinline__ int load_idx(const void* p, long long i, int is64) {
    if (is64) return (int)((const long long*)p)[i];
    return ((const int*)p)[i];
}

// Detect whether integer inputs are int64 (8B) or int32 (4B).
__global__ void detect_dtype_kernel(const void* __restrict__ edge, int* __restrict__ flag, int n_nodes) {
    __shared__ int cnt;
    if (threadIdx.x == 0) cnt = 0;
    __syncthreads();
    long long v = ((const long long*)edge)[threadIdx.x];
    int ok = (v >= 0 && v < (long long)n_nodes) ? 1 : 0;
    atomicAdd(&cnt, ok);
    __syncthreads();
    if (threadIdx.x == 0) *flag = (cnt > 128) ? 1 : 0;
}

__global__ void zero_int_kernel(int* __restrict__ p, int n) {
    int i = blockIdx.x * blockDim.x + threadIdx.x;
    if (i < n) p[i] = 0;
}

// count in-degree (excluding the analytic self-loop): cnt[col[e]]++
__global__ void count_kernel(const void* __restrict__ edge, const int* __restrict__ flag,
                             int* __restrict__ cnt, int e_total) {
    int i = blockIdx.x * blockDim.x + threadIdx.x;
    if (i >= e_total) return;
    int f = *flag;
    int c = load_idx(edge, (long long)e_total + i, f);
    atomicAdd(&cnt[c], 1);
}

// ---- hierarchical scan: pass 1 = per-block sums ----
__global__ __launch_bounds__(SCAN_BS) void scan1_kernel(const int* __restrict__ cnt,
                                                        int* __restrict__ blockSums, int n) {
    __shared__ int red[SCAN_BS];
    int i = blockIdx.x * SCAN_BS + threadIdx.x;
    int v = (i < n) ? cnt[i] : 0;
    red[threadIdx.x] = v;
    __syncthreads();
    for (int off = SCAN_BS / 2; off > 0; off >>= 1) {
        if (threadIdx.x < off) red[threadIdx.x] += red[threadIdx.x + off];
        __syncthreads();
    }
    if (threadIdx.x == 0) blockSums[blockIdx.x] = red[0];
}

// ---- pass 2: exclusive scan of the (<=1024) block sums in one block ----
__global__ __launch_bounds__(1024) void scan2_kernel(int* __restrict__ blockSums,
                                                     int* __restrict__ rowptr, int nb, int n) {
    __shared__ int part[1024];
    int t = threadIdx.x;
    int v = (t < nb) ? blockSums[t] : 0;
    part[t] = v;
    __syncthreads();
    for (int off = 1; off < 1024; off <<= 1) {
        int u = (t >= off) ? part[t - off] : 0;
        __syncthreads();
        part[t] += u;
        __syncthreads();
    }
    if (t < nb) blockSums[t] = part[t] - v;     // exclusive block offset
    if (t == nb - 1) rowptr[n] = part[t];       // total = E
}

// ---- pass 3: per-block exclusive scan + block offset; emit rowptr/fillpos/dinv ----
__global__ __launch_bounds__(SCAN_BS) void scan3_kernel(const int* __restrict__ cnt,
                                                        const int* __restrict__ blockSums,
                                                        int* __restrict__ rowptr,
                                                        int* __restrict__ fillpos,
                                                        float* __restrict__ dinv, int n) {
    __shared__ int part[SCAN_BS];
    int t = threadIdx.x;
    int i = blockIdx.x * SCAN_BS + t;
    int v = (i < n) ? cnt[i] : 0;
    part[t] = v;
    __syncthreads();
    for (int off = 1; off < SCAN_BS; off <<= 1) {
        int u = (t >= off) ? part[t - off] : 0;
        __syncthreads();
        part[t] += u;
        __syncthreads();
    }
    if (i < n) {
        int ex = part[t] - v + blockSums[blockIdx.x];
        rowptr[i] = ex;
        fillpos[i] = ex;
        dinv[i] = rsqrtf((float)(v + 1));
    }
}

// scatter edges into CSR (grouped by destination col), weight = dinv[row]*dinv[col]
__global__ void fill_kernel(const void* __restrict__ edge, const int* __restrict__ flag,
                            const float* __restrict__ dinv, int* __restrict__ fillpos,
                            int* __restrict__ src, float* __restrict__ w, int e_total) {
    int i = blockIdx.x * blockDim.x + threadIdx.x;
    if (i >= e_total) return;
    int f = *flag;
    int r = load_idx(edge, i, f);
    int c = load_idx(edge, (long long)e_total + i, f);
    int p = atomicAdd(&fillpos[c], 1);
    src[p] = r;
    w[p] = dinv[r] * dinv[c];
}

// out[N,32] = in[N,32] @ W[32,32]
__global__ __launch_bounds__(256) void gemm32_kernel(const float* __restrict__ in,
                                                     const float* __restrict__ W,
                                                     float* __restrict__ out, int n) {
    __shared__ float sW[32 * 32];
    __shared__ float sIn[64 * 33];
    int t = threadIdx.x;
    for (int i = t; i < 1024; i += 256) sW[i] = W[i];
    int base = blockIdx.x * 64;
    int nn = min(64, n - base);
    for (int i = t; i < nn * 32; i += 256) {
        int node = i >> 5, j = i & 31;
        sIn[node * 33 + j] = in[(size_t)(base + node) * 32 + j];
    }
    __syncthreads();
    int node = t & 63;
    int k0 = (t >> 6) * 8;
    if (node < nn) {
        float acc[8] = {0, 0, 0, 0, 0, 0, 0, 0};
        #pragma unroll
        for (int j = 0; j < 32; ++j) {
            float a = sIn[node * 33 + j];
            #pragma unroll
            for (int kk = 0; kk < 8; ++kk) acc[kk] = fmaf(a, sW[j * 32 + k0 + kk], acc[kk]);
        }
        float* op = out + (size_t)(base + node) * 32 + k0;
        *(float4*)op = make_float4(acc[0], acc[1], acc[2], acc[3]);
        *(float4*)(op + 4) = make_float4(acc[4], acc[5], acc[6], acc[7]);
    }
}

// out[c] = relu( sum_{e in CSR[c]} w_e * hw[src_e] + dinv[c]^2 * hw[c] + bias (+ res[c]) )
template <int HAS_RES>
__global__ __launch_bounds__(256) void agg_kernel(const float* __restrict__ hw,
                                                  const int* __restrict__ rowptr,
                                                  const int* __restrict__ src,
                                                  const float* __restrict__ w,
                                                  const float* __restrict__ dinv,
                                                  const float* __restrict__ bias,
                                                  const float* __restrict__ res,
                                                  float* __restrict__ out, int n) {
    int g = blockIdx.x * 8 + (threadIdx.x >> 5);
    int k = threadIdx.x & 31;
    if (g >= n) return;
    float di = dinv[g];
    float acc = di * di * hw[(size_t)g * 32 + k];
    int s = rowptr[g], e = rowptr[g + 1];
    int p = s;
    for (; p + 3 < e; p += 4) {
        int sr0 = src[p];
        int sr1 = src[p + 1];
        int sr2 = src[p + 2];
        int sr3 = src[p + 3];
        float w0 = w[p];
        float w1 = w[p + 1];
        float w2 = w[p + 2];
        float w3 = w[p + 3];
        float v0 = hw[(size_t)sr0 * 32 + k];
        float v1 = hw[(size_t)sr1 * 32 + k];
        float v2 = hw[(size_t)sr2 * 32 + k];
        float v3 = hw[(size_t)sr3 * 32 + k];
        acc = fmaf(w0, v0, acc);
        acc = fmaf(w1, v1, acc);
        acc = fmaf(w2, v2, acc);
        acc = fmaf(w3, v3, acc);
    }
    for (; p < e; ++p) {
        int sr = src[p];
        acc = fmaf(w[p], hw[(size_t)sr * 32 + k], acc);
    }
    acc += bias[k];
    if (HAS_RES) acc += res[(size_t)g * 32 + k];
    out[(size_t)g * 32 + k] = fmaxf(acc, 0.0f);
}

// one block per graph: mean-pool (batch is sorted -> binary search range) + 32->128 FC
__global__ __launch_bounds__(128) void pool_fc_kernel(const float* __restrict__ h,
                                                      const void* __restrict__ batch,
                                                      const int* __restrict__ flag,
                                                      const float* __restrict__ Wl,
                                                      const float* __restrict__ bl,
                                                      float* __restrict__ out, int n) {
    __shared__ float red[4][32];
    __shared__ float sp[32];
    __shared__ int srange[2];
    int g = blockIdx.x;
    int t = threadIdx.x;
    int f = *flag;
    if (t < 2) {
        int target = g + t;
        int lo = 0, hi = n;
        while (lo < hi) {
            int mid = (lo + hi) >> 1;
            int v = load_idx(batch, mid, f);
            if (v < target) lo = mid + 1; else hi = mid;
        }
        srange[t] = lo;
    }
    __syncthreads();
    int s = srange[0], e = srange[1];
    int gi = t >> 5, k = t & 31;
    float acc = 0.f;
    for (int i = s + gi; i < e; i += 4) acc += h[(size_t)i * 32 + k];
    red[gi][k] = acc;
    __syncthreads();
    if (gi == 0) {
        float v = red[0][k] + red[1][k] + red[2][k] + red[3][k];
        sp[k] = v / fmaxf((float)(e - s), 1.0f);
    }
    __syncthreads();
    float val = bl[t];
    #pragma unroll
    for (int j = 0; j < 32; ++j) val = fmaf(sp[j], Wl[j * 128 + t], val);
    out[(size_t)g * 128 + t] = val;
}

extern "C" void kernel_launch(void* const* d_in, const int* in_sizes, int n_in,
                              void* d_out, int out_size, void* d_ws, size_t ws_size,
                              hipStream_t stream) {
    const float* x = (const float*)d_in[0];
    const void* edge = d_in[1];
    const void* batch = d_in[2];
    const float* W[6] = {(const float*)d_in[3], (const float*)d_in[5],
                         (const float*)d_in[7], (const float*)d_in[9],
                         (const float*)d_in[11], (const float*)d_in[13]};
    const float* B[6] = {(const float*)d_in[4], (const float*)d_in[6],
                         (const float*)d_in[8], (const float*)d_in[10],
                         (const float*)d_in[12], (const float*)d_in[14]};
    const float* Wl = (const float*)d_in[15];
    const float* bl = (const float*)d_in[16];
    float* out = (float*)d_out;

    int n = in_sizes[0] / DIM;      // 100000 nodes
    int eN = in_sizes[1] / 2;       // 3200000 edges
    int gN = out_size / OUTD;       // 8192 graphs

    char* ws = (char*)d_ws;
    size_t off = 0;
    auto alloc = [&](size_t bytes) {
        void* p = ws + off;
        off += (bytes + 255) & ~(size_t)255;
        return p;
    };
    int* flag      = (int*)alloc(4);
    int* cnt       = (int*)alloc((size_t)n * 4);
    int* rowptr    = (int*)alloc((size_t)(n + 1) * 4);
    int* fillpos   = (int*)alloc((size_t)n * 4);
    float* dinv    = (float*)alloc((size_t)n * 4);
    int* blockSums = (int*)alloc(1024 * 4);
    int* csr_src   = (int*)alloc((size_t)eN * 4);
    float* csr_w   = (float*)alloc((size_t)eN * 4);
    float* bufA    = (float*)alloc((size_t)n * DIM * 4);
    float* bufB    = (float*)alloc((size_t)n * DIM * 4);
    float* bufC    = (float*)alloc((size_t)n * DIM * 4);

    int nb = (n + SCAN_BS - 1) / SCAN_BS;   // 196 <= 1024

    detect_dtype_kernel<<<1, 256, 0, stream>>>(edge, flag, n);
    zero_int_kernel<<<(n + 255) / 256, 256, 0, stream>>>(cnt, n);
    count_kernel<<<(eN + 255) / 256, 256, 0, stream>>>(edge, flag, cnt, eN);
    scan1_kernel<<<nb, SCAN_BS, 0, stream>>>(cnt, blockSums, n);
    scan2_kernel<<<1, 1024, 0, stream>>>(blockSums, rowptr, nb, n);
    scan3_kernel<<<nb, SCAN_BS, 0, stream>>>(cnt, blockSums, rowptr, fillpos, dinv, n);
    fill_kernel<<<(eN + 255) / 256, 256, 0, stream>>>(edge, flag, dinv, fillpos, csr_src, csr_w, eN);

    int gb = (n + 63) / 64;
    int ab = (n + 7) / 8;

    // Res-block 1 (residual = x)
    gemm32_kernel<<<gb, 256, 0, stream>>>(x, W[0], bufC, n);
    agg_kernel<0><<<ab, 256, 0, stream>>>(bufC, rowptr, csr_src, csr_w, dinv, B[0], nullptr, bufA, n);
    gemm32_kernel<<<gb, 256, 0, stream>>>(bufA, W[1], bufC, n);
    agg_kernel<1><<<ab, 256, 0, stream>>>(bufC, rowptr, csr_src, csr_w, dinv, B[1], x, bufB, n);
    // Res-block 2 (residual = bufB)
    gemm32_kernel<<<gb, 256, 0, stream>>>(bufB, W[2], bufC, n);
    agg_kernel<0><<<ab, 256, 0, stream>>>(bufC, rowptr, csr_src, csr_w, dinv, B[2], nullptr, bufA, n);
    gemm32_kernel<<<gb, 256, 0, stream>>>(bufA, W[3], bufC, n);
    agg_kernel<1><<<ab, 256, 0, stream>>>(bufC, rowptr, csr_src, csr_w, dinv, B[3], bufB, bufA, n);
    // Res-block 3 (residual = bufA)
    gemm32_kernel<<<gb, 256, 0, stream>>>(bufA, W[4], bufC, n);
    agg_kernel<0><<<ab, 256, 0, stream>>>(bufC, rowptr, csr_src, csr_w, dinv, B[4], nullptr, bufB, n);
    gemm32_kernel<<<gb, 256, 0, stream>>>(bufB, W[5], bufC, n);
    agg_kernel<1><<<ab, 256, 0, stream>>>(bufC, rowptr, csr_src, csr_w, dinv, B[5], bufA, bufB, n);

    pool_fc_kernel<<<gN, 128, 0, stream>>>(bufB, batch, flag, Wl, bl, out, n);
}

// Round 3
// 883.479 us; speedup vs baseline: 1.5414x; 1.0291x over previous
//
#include <hip/hip_runtime.h>
#include <hip/hip_bf16.h>
#include <cstdint>

#define DIM 32
#define OUTD 128
#define SCAN_BS 512

// ---------------- index-load helper (int32 vs int64 inputs) ----------------
__device__ __forceinline__ int load_idx(const void* p, long long i, int is64) {
    if (is64) return (int)((const long long*)p)[i];
    return ((const int*)p)[i];
}

// Detect whether integer inputs are int64 (8B) or int32 (4B).
__global__ void detect_dtype_kernel(const void* __restrict__ edge, int* __restrict__ flag, int n_nodes) {
    __shared__ int cnt;
    if (threadIdx.x == 0) cnt = 0;
    __syncthreads();
    long long v = ((const long long*)edge)[threadIdx.x];
    int ok = (v >= 0 && v < (long long)n_nodes) ? 1 : 0;
    atomicAdd(&cnt, ok);
    __syncthreads();
    if (threadIdx.x == 0) *flag = (cnt > 128) ? 1 : 0;
}

__global__ void zero_int_kernel(int* __restrict__ p, int n) {
    int i = blockIdx.x * blockDim.x + threadIdx.x;
    if (i < n) p[i] = 0;
}

// count in-degree (excluding the analytic self-loop): cnt[col[e]]++
__global__ void count_kernel(const void* __restrict__ edge, const int* __restrict__ flag,
                             int* __restrict__ cnt, int e_total) {
    int i = blockIdx.x * blockDim.x + threadIdx.x;
    if (i >= e_total) return;
    int f = *flag;
    int c = load_idx(edge, (long long)e_total + i, f);
    atomicAdd(&cnt[c], 1);
}

// ---- hierarchical scan: pass 1 = per-block sums ----
__global__ __launch_bounds__(SCAN_BS) void scan1_kernel(const int* __restrict__ cnt,
                                                        int* __restrict__ blockSums, int n) {
    __shared__ int red[SCAN_BS];
    int i = blockIdx.x * SCAN_BS + threadIdx.x;
    int v = (i < n) ? cnt[i] : 0;
    red[threadIdx.x] = v;
    __syncthreads();
    for (int off = SCAN_BS / 2; off > 0; off >>= 1) {
        if (threadIdx.x < off) red[threadIdx.x] += red[threadIdx.x + off];
        __syncthreads();
    }
    if (threadIdx.x == 0) blockSums[blockIdx.x] = red[0];
}

// ---- pass 2: exclusive scan of the (<=1024) block sums in one block ----
__global__ __launch_bounds__(1024) void scan2_kernel(int* __restrict__ blockSums,
                                                     int* __restrict__ rowptr, int nb, int n) {
    __shared__ int part[1024];
    int t = threadIdx.x;
    int v = (t < nb) ? blockSums[t] : 0;
    part[t] = v;
    __syncthreads();
    for (int off = 1; off < 1024; off <<= 1) {
        int u = (t >= off) ? part[t - off] : 0;
        __syncthreads();
        part[t] += u;
        __syncthreads();
    }
    if (t < nb) blockSums[t] = part[t] - v;     // exclusive block offset
    if (t == nb - 1) rowptr[n] = part[t];       // total = E
}

// ---- pass 3: per-block exclusive scan + block offset; emit rowptr/fillpos/dinv ----
__global__ __launch_bounds__(SCAN_BS) void scan3_kernel(const int* __restrict__ cnt,
                                                        const int* __restrict__ blockSums,
                                                        int* __restrict__ rowptr,
                                                        int* __restrict__ fillpos,
                                                        float* __restrict__ dinv, int n) {
    __shared__ int part[SCAN_BS];
    int t = threadIdx.x;
    int i = blockIdx.x * SCAN_BS + t;
    int v = (i < n) ? cnt[i] : 0;
    part[t] = v;
    __syncthreads();
    for (int off = 1; off < SCAN_BS; off <<= 1) {
        int u = (t >= off) ? part[t - off] : 0;
        __syncthreads();
        part[t] += u;
        __syncthreads();
    }
    if (i < n) {
        int ex = part[t] - v + blockSums[blockIdx.x];
        rowptr[i] = ex;
        fillpos[i] = ex;
        dinv[i] = rsqrtf((float)(v + 1));
    }
}

// scatter edges into CSR (grouped by destination col); src index only
__global__ void fill_kernel(const void* __restrict__ edge, const int* __restrict__ flag,
                            int* __restrict__ fillpos,
                            int* __restrict__ src, int e_total) {
    int i = blockIdx.x * blockDim.x + threadIdx.x;
    if (i >= e_total) return;
    int f = *flag;
    int r = load_idx(edge, i, f);
    int c = load_idx(edge, (long long)e_total + i, f);
    int p = atomicAdd(&fillpos[c], 1);
    src[p] = r;
}

// Fused GCN conv: out[c] = relu( [dinv_c*(sum_e dinv_r*h[r] + dinv_c*h[c])] @ W + b (+ res) )
// 8 nodes/block, 32 lanes per node (lane = feature). W column k kept in registers.
template <int HAS_RES>
__global__ __launch_bounds__(256) void fused_conv_kernel(const float* __restrict__ h,
                                                         const int* __restrict__ rowptr,
                                                         const int* __restrict__ src,
                                                         const float* __restrict__ dinv,
                                                         const float* __restrict__ W,
                                                         const float* __restrict__ bias,
                                                         const float* __restrict__ res,
                                                         float* __restrict__ out, int n) {
    int t = threadIdx.x;
    int k = t & 31;
    // Stage column k of W into registers (coalesced; latency hidden under edge loop)
    float wr[32];
    #pragma unroll
    for (int j = 0; j < 32; ++j) wr[j] = W[j * 32 + k];
    float bk = bias[k];
    int g = blockIdx.x * 8 + (t >> 5);
    if (g >= n) return;
    float di = dinv[g];
    float self = h[(size_t)g * 32 + k];
    float acc = 0.f;
    int s = rowptr[g], e = rowptr[g + 1];
    int p = s;
    for (; p + 3 < e; p += 4) {
        int sr0 = src[p];
        int sr1 = src[p + 1];
        int sr2 = src[p + 2];
        int sr3 = src[p + 3];
        float d0 = dinv[sr0];
        float d1 = dinv[sr1];
        float d2 = dinv[sr2];
        float d3 = dinv[sr3];
        float v0 = h[(size_t)sr0 * 32 + k];
        float v1 = h[(size_t)sr1 * 32 + k];
        float v2 = h[(size_t)sr2 * 32 + k];
        float v3 = h[(size_t)sr3 * 32 + k];
        acc = fmaf(d0, v0, acc);
        acc = fmaf(d1, v1, acc);
        acc = fmaf(d2, v2, acc);
        acc = fmaf(d3, v3, acc);
    }
    for (; p < e; ++p) {
        int sr = src[p];
        acc = fmaf(dinv[sr], h[(size_t)sr * 32 + k], acc);
    }
    acc = di * fmaf(di, self, acc);   // aggregated feature k of node g
    // mini-GEMM across the 32-lane group: o_k = b_k + sum_j agg_j * W[j][k]
    float o = bk;
    #pragma unroll
    for (int j = 0; j < 32; ++j) {
        float aj = __shfl(acc, j, 32);
        o = fmaf(aj, wr[j], o);
    }
    if (HAS_RES) o += res[(size_t)g * 32 + k];
    out[(size_t)g * 32 + k] = fmaxf(o, 0.f);
}

// one block per graph: mean-pool (batch is sorted -> binary search range) + 32->128 FC
__global__ __launch_bounds__(128) void pool_fc_kernel(const float* __restrict__ h,
                                                      const void* __restrict__ batch,
                                                      const int* __restrict__ flag,
                                                      const float* __restrict__ Wl,
                                                      const float* __restrict__ bl,
                                                      float* __restrict__ out, int n) {
    __shared__ float red[4][32];
    __shared__ float sp[32];
    __shared__ int srange[2];
    int g = blockIdx.x;
    int t = threadIdx.x;
    int f = *flag;
    if (t < 2) {
        int target = g + t;
        int lo = 0, hi = n;
        while (lo < hi) {
            int mid = (lo + hi) >> 1;
            int v = load_idx(batch, mid, f);
            if (v < target) lo = mid + 1; else hi = mid;
        }
        srange[t] = lo;
    }
    __syncthreads();
    int s = srange[0], e = srange[1];
    int gi = t >> 5, k = t & 31;
    float acc = 0.f;
    for (int i = s + gi; i < e; i += 4) acc += h[(size_t)i * 32 + k];
    red[gi][k] = acc;
    __syncthreads();
    if (gi == 0) {
        float v = red[0][k] + red[1][k] + red[2][k] + red[3][k];
        sp[k] = v / fmaxf((float)(e - s), 1.0f);
    }
    __syncthreads();
    float val = bl[t];
    #pragma unroll
    for (int j = 0; j < 32; ++j) val = fmaf(sp[j], Wl[j * 128 + t], val);
    out[(size_t)g * 128 + t] = val;
}

extern "C" void kernel_launch(void* const* d_in, const int* in_sizes, int n_in,
                              void* d_out, int out_size, void* d_ws, size_t ws_size,
                              hipStream_t stream) {
    const float* x = (const float*)d_in[0];
    const void* edge = d_in[1];
    const void* batch = d_in[2];
    const float* W[6] = {(const float*)d_in[3], (const float*)d_in[5],
                         (const float*)d_in[7], (const float*)d_in[9],
                         (const float*)d_in[11], (const float*)d_in[13]};
    const float* B[6] = {(const float*)d_in[4], (const float*)d_in[6],
                         (const float*)d_in[8], (const float*)d_in[10],
                         (const float*)d_in[12], (const float*)d_in[14]};
    const float* Wl = (const float*)d_in[15];
    const float* bl = (const float*)d_in[16];
    float* out = (float*)d_out;

    int n = in_sizes[0] / DIM;      // 100000 nodes
    int eN = in_sizes[1] / 2;       // 3200000 edges
    int gN = out_size / OUTD;       // 8192 graphs

    char* ws = (char*)d_ws;
    size_t off = 0;
    auto alloc = [&](size_t bytes) {
        void* p = ws + off;
        off += (bytes + 255) & ~(size_t)255;
        return p;
    };
    int* flag      = (int*)alloc(4);
    int* cnt       = (int*)alloc((size_t)n * 4);
    int* rowptr    = (int*)alloc((size_t)(n + 1) * 4);
    int* fillpos   = (int*)alloc((size_t)n * 4);
    float* dinv    = (float*)alloc((size_t)n * 4);
    int* blockSums = (int*)alloc(1024 * 4);
    int* csr_src   = (int*)alloc((size_t)eN * 4);
    float* bufA    = (float*)alloc((size_t)n * DIM * 4);
    float* bufB    = (float*)alloc((size_t)n * DIM * 4);
    float* bufC    = (float*)alloc((size_t)n * DIM * 4);

    int nb = (n + SCAN_BS - 1) / SCAN_BS;   // 196 <= 1024

    detect_dtype_kernel<<<1, 256, 0, stream>>>(edge, flag, n);
    zero_int_kernel<<<(n + 255) / 256, 256, 0, stream>>>(cnt, n);
    count_kernel<<<(eN + 255) / 256, 256, 0, stream>>>(edge, flag, cnt, eN);
    scan1_kernel<<<nb, SCAN_BS, 0, stream>>>(cnt, blockSums, n);
    scan2_kernel<<<1, 1024, 0, stream>>>(blockSums, rowptr, nb, n);
    scan3_kernel<<<nb, SCAN_BS, 0, stream>>>(cnt, blockSums, rowptr, fillpos, dinv, n);
    fill_kernel<<<(eN + 255) / 256, 256, 0, stream>>>(edge, flag, fillpos, csr_src, eN);

    int ab = (n + 7) / 8;

    // Res-block 1 (residual = x): x -> bufA -> bufB
    fused_conv_kernel<0><<<ab, 256, 0, stream>>>(x,    rowptr, csr_src, dinv, W[0], B[0], nullptr, bufA, n);
    fused_conv_kernel<1><<<ab, 256, 0, stream>>>(bufA, rowptr, csr_src, dinv, W[1], B[1], x,       bufB, n);
    // Res-block 2 (residual = bufB): bufB -> bufA -> bufC
    fused_conv_kernel<0><<<ab, 256, 0, stream>>>(bufB, rowptr, csr_src, dinv, W[2], B[2], nullptr, bufA, n);
    fused_conv_kernel<1><<<ab, 256, 0, stream>>>(bufA, rowptr, csr_src, dinv, W[3], B[3], bufB,    bufC, n);
    // Res-block 3 (residual = bufC): bufC -> bufA -> bufB
    fused_conv_kernel<0><<<ab, 256, 0, stream>>>(bufC, rowptr, csr_src, dinv, W[4], B[4], nullptr, bufA, n);
    fused_conv_kernel<1><<<ab, 256, 0, stream>>>(bufA, rowptr, csr_src, dinv, W[5], B[5], bufC,    bufB, n);

    pool_fc_kernel<<<gN, 128, 0, stream>>>(bufB, batch, flag, Wl, bl, out, n);
}

// Round 4
// 558.036 us; speedup vs baseline: 2.4403x; 1.5832x over previous
//
#include <hip/hip_runtime.h>
#include <hip/hip_bf16.h>
#include <cstdint>

#define DIM 32
#define OUTD 128
#define B_PART 256     // blocks in hist/partition passes
#define BSHIFT 9       // bucket = 512 nodes

// ---------------- index-load helper (int32 vs int64 inputs) ----------------
__device__ __forceinline__ int load_idx(const void* p, long long i, int is64) {
    if (is64) return (int)((const long long*)p)[i];
    return ((const int*)p)[i];
}

// Detect whether integer inputs are int64 (8B) or int32 (4B).
__global__ void detect_dtype_kernel(const void* __restrict__ edge, int* __restrict__ flag, int n_nodes) {
    __shared__ int cnt;
    if (threadIdx.x == 0) cnt = 0;
    __syncthreads();
    long long v = ((const long long*)edge)[threadIdx.x];
    int ok = (v >= 0 && v < (long long)n_nodes) ? 1 : 0;
    atomicAdd(&cnt, ok);
    __syncthreads();
    if (threadIdx.x == 0) *flag = (cnt > 128) ? 1 : 0;
}

// ---- pass 1: per-(bucket, block) histogram of destination buckets ----
__global__ __launch_bounds__(256) void hist_kernel(const void* __restrict__ edge,
                                                   const int* __restrict__ flag,
                                                   int* __restrict__ histT,
                                                   int eN, int NB, int chunk) {
    __shared__ int sh[256];
    int t = threadIdx.x, bid = blockIdx.x;
    sh[t] = 0;
    __syncthreads();
    int f = *flag;
    int s = bid * chunk, e = min(eN, s + chunk);
    for (int i = s + t; i < e; i += 256) {
        int c = load_idx(edge, (long long)eN + i, f);
        atomicAdd(&sh[c >> BSHIFT], 1);
    }
    __syncthreads();
    if (t < NB) histT[t * B_PART + bid] = sh[t];   // bucket-major layout
}

// ---- generic hierarchical exclusive scan over M ints (A: block sums) ----
__global__ __launch_bounds__(512) void scanA_kernel(const int* __restrict__ a,
                                                    int* __restrict__ sums, int M) {
    __shared__ int red[512];
    int i = blockIdx.x * 512 + threadIdx.x;
    int v = (i < M) ? a[i] : 0;
    red[threadIdx.x] = v;
    __syncthreads();
    for (int off = 256; off > 0; off >>= 1) {
        if (threadIdx.x < off) red[threadIdx.x] += red[threadIdx.x + off];
        __syncthreads();
    }
    if (threadIdx.x == 0) sums[blockIdx.x] = red[0];
}

// ---- B: exclusive scan of block sums (<=1024) ----
__global__ __launch_bounds__(1024) void scanB_kernel(int* __restrict__ sums, int nb) {
    __shared__ int part[1024];
    int t = threadIdx.x;
    int v = (t < nb) ? sums[t] : 0;
    part[t] = v;
    __syncthreads();
    for (int off = 1; off < 1024; off <<= 1) {
        int u = (t >= off) ? part[t - off] : 0;
        __syncthreads();
        part[t] += u;
        __syncthreads();
    }
    if (t < nb) sums[t] = part[t] - v;
}

// ---- C: apply (in-place exclusive scan) ----
__global__ __launch_bounds__(512) void scanC_kernel(int* __restrict__ a,
                                                    const int* __restrict__ sums, int M) {
    __shared__ int part[512];
    int t = threadIdx.x;
    int i = blockIdx.x * 512 + t;
    int v = (i < M) ? a[i] : 0;
    part[t] = v;
    __syncthreads();
    for (int off = 1; off < 512; off <<= 1) {
        int u = (t >= off) ? part[t - off] : 0;
        __syncthreads();
        part[t] += u;
        __syncthreads();
    }
    if (i < M) a[i] = part[t] - v + sums[blockIdx.x];
}

// ---- pass 2: partition edges into bucket runs; pack (r | local_c<<23) in 4B ----
__global__ __launch_bounds__(256) void partition_kernel(const void* __restrict__ edge,
                                                        const int* __restrict__ flag,
                                                        const int* __restrict__ offs,
                                                        unsigned int* __restrict__ pairs,
                                                        int eN, int NB, int chunk) {
    __shared__ int cur[256];
    int t = threadIdx.x, bid = blockIdx.x;
    if (t < NB) cur[t] = offs[t * B_PART + bid];
    __syncthreads();
    int f = *flag;
    int s = bid * chunk, e = min(eN, s + chunk);
    for (int i = s + t; i < e; i += 256) {
        int r = load_idx(edge, i, f);
        int c = load_idx(edge, (long long)eN + i, f);
        int slot = atomicAdd(&cur[c >> BSHIFT], 1);
        pairs[slot] = (unsigned)r | ((unsigned)(c & 511) << 23);
    }
}

// ---- pass 3: per-bucket CSR build (rowptr, dinv, csr_src) with L2-local writes ----
__global__ __launch_bounds__(256) void bucket_fill_kernel(const unsigned int* __restrict__ pairs,
                                                          const int* __restrict__ offs,
                                                          int* __restrict__ rowptr,
                                                          float* __restrict__ dinv,
                                                          int* __restrict__ csr_src,
                                                          int n, int eN, int NB) {
    __shared__ int lcnt[512];
    __shared__ int lofs[512];
    __shared__ int psum[256];
    int t = threadIdx.x, b = blockIdx.x;
    int base = b << BSHIFT;
    int nLocal = min(512, n - base);
    int s = offs[b * B_PART];
    int e = (b + 1 < NB) ? offs[(b + 1) * B_PART] : eN;
    lcnt[t] = 0;
    lcnt[t + 256] = 0;
    __syncthreads();
    for (int i = s + t; i < e; i += 256) atomicAdd(&lcnt[pairs[i] >> 23], 1);
    __syncthreads();
    int a0 = lcnt[2 * t], a1 = lcnt[2 * t + 1];
    psum[t] = a0 + a1;
    __syncthreads();
    for (int off = 1; off < 256; off <<= 1) {
        int u = (t >= off) ? psum[t - off] : 0;
        __syncthreads();
        psum[t] += u;
        __syncthreads();
    }
    int ex = psum[t] - (a0 + a1);
    lofs[2 * t] = ex;
    lofs[2 * t + 1] = ex + a0;
    __syncthreads();
    for (int j = t; j < nLocal; j += 256) {
        rowptr[base + j] = s + lofs[j];
        dinv[base + j] = rsqrtf((float)(lcnt[j] + 1));
    }
    if (b == NB - 1 && t == 0) rowptr[n] = eN;
    __syncthreads();
    lcnt[t] = lofs[t];
    lcnt[t + 256] = lofs[t + 256];
    __syncthreads();
    for (int i = s + t; i < e; i += 256) {
        unsigned p = pairs[i];
        int lc = (int)(p >> 23);
        int r = (int)(p & 0x7FFFFFu);
        int slot = atomicAdd(&lcnt[lc], 1);
        csr_src[s + slot] = r;
    }
}

// Fused GCN conv: out[c] = relu( [dinv_c*(sum_e dinv_r*h[r] + dinv_c*h[c])] @ W + b (+ res) )
// 8 nodes/block, 32 lanes per node (lane = feature). W column k kept in registers.
template <int HAS_RES>
__global__ __launch_bounds__(256) void fused_conv_kernel(const float* __restrict__ h,
                                                         const int* __restrict__ rowptr,
                                                         const int* __restrict__ src,
                                                         const float* __restrict__ dinv,
                                                         const float* __restrict__ W,
                                                         const float* __restrict__ bias,
                                                         const float* __restrict__ res,
                                                         float* __restrict__ out, int n) {
    int t = threadIdx.x;
    int k = t & 31;
    float wr[32];
    #pragma unroll
    for (int j = 0; j < 32; ++j) wr[j] = W[j * 32 + k];
    float bk = bias[k];
    int g = blockIdx.x * 8 + (t >> 5);
    if (g >= n) return;
    float di = dinv[g];
    float self = h[(size_t)g * 32 + k];
    float acc = 0.f;
    int s = rowptr[g], e = rowptr[g + 1];
    int p = s;
    for (; p + 3 < e; p += 4) {
        int sr0 = src[p];
        int sr1 = src[p + 1];
        int sr2 = src[p + 2];
        int sr3 = src[p + 3];
        float d0 = dinv[sr0];
        float d1 = dinv[sr1];
        float d2 = dinv[sr2];
        float d3 = dinv[sr3];
        float v0 = h[(size_t)sr0 * 32 + k];
        float v1 = h[(size_t)sr1 * 32 + k];
        float v2 = h[(size_t)sr2 * 32 + k];
        float v3 = h[(size_t)sr3 * 32 + k];
        acc = fmaf(d0, v0, acc);
        acc = fmaf(d1, v1, acc);
        acc = fmaf(d2, v2, acc);
        acc = fmaf(d3, v3, acc);
    }
    for (; p < e; ++p) {
        int sr = src[p];
        acc = fmaf(dinv[sr], h[(size_t)sr * 32 + k], acc);
    }
    acc = di * fmaf(di, self, acc);
    float o = bk;
    #pragma unroll
    for (int j = 0; j < 32; ++j) {
        float aj = __shfl(acc, j, 32);
        o = fmaf(aj, wr[j], o);
    }
    if (HAS_RES) o += res[(size_t)g * 32 + k];
    out[(size_t)g * 32 + k] = fmaxf(o, 0.f);
}

// one block per graph: mean-pool (batch is sorted -> binary search range) + 32->128 FC
__global__ __launch_bounds__(128) void pool_fc_kernel(const float* __restrict__ h,
                                                      const void* __restrict__ batch,
                                                      const int* __restrict__ flag,
                                                      const float* __restrict__ Wl,
                                                      const float* __restrict__ bl,
                                                      float* __restrict__ out, int n) {
    __shared__ float red[4][32];
    __shared__ float sp[32];
    __shared__ int srange[2];
    int g = blockIdx.x;
    int t = threadIdx.x;
    int f = *flag;
    if (t < 2) {
        int target = g + t;
        int lo = 0, hi = n;
        while (lo < hi) {
            int mid = (lo + hi) >> 1;
            int v = load_idx(batch, mid, f);
            if (v < target) lo = mid + 1; else hi = mid;
        }
        srange[t] = lo;
    }
    __syncthreads();
    int s = srange[0], e = srange[1];
    int gi = t >> 5, k = t & 31;
    float acc = 0.f;
    for (int i = s + gi; i < e; i += 4) acc += h[(size_t)i * 32 + k];
    red[gi][k] = acc;
    __syncthreads();
    if (gi == 0) {
        float v = red[0][k] + red[1][k] + red[2][k] + red[3][k];
        sp[k] = v / fmaxf((float)(e - s), 1.0f);
    }
    __syncthreads();
    float val = bl[t];
    #pragma unroll
    for (int j = 0; j < 32; ++j) val = fmaf(sp[j], Wl[j * 128 + t], val);
    out[(size_t)g * 128 + t] = val;
}

extern "C" void kernel_launch(void* const* d_in, const int* in_sizes, int n_in,
                              void* d_out, int out_size, void* d_ws, size_t ws_size,
                              hipStream_t stream) {
    const float* x = (const float*)d_in[0];
    const void* edge = d_in[1];
    const void* batch = d_in[2];
    const float* W[6] = {(const float*)d_in[3], (const float*)d_in[5],
                         (const float*)d_in[7], (const float*)d_in[9],
                         (const float*)d_in[11], (const float*)d_in[13]};
    const float* B[6] = {(const float*)d_in[4], (const float*)d_in[6],
                         (const float*)d_in[8], (const float*)d_in[10],
                         (const float*)d_in[12], (const float*)d_in[14]};
    const float* Wl = (const float*)d_in[15];
    const float* bl = (const float*)d_in[16];
    float* out = (float*)d_out;

    int n = in_sizes[0] / DIM;      // 100000 nodes
    int eN = in_sizes[1] / 2;       // 3200000 edges
    int gN = out_size / OUTD;       // 8192 graphs

    int NB = (n + 511) >> BSHIFT;   // 196 buckets (<=256 for n<=131072)
    int M = NB * B_PART;            // hist matrix size
    int chunk = (eN + B_PART - 1) / B_PART;
    int nbA = (M + 511) / 512;

    char* ws = (char*)d_ws;
    size_t off = 0;
    auto alloc = [&](size_t bytes) {
        void* p = ws + off;
        off += (bytes + 255) & ~(size_t)255;
        return p;
    };
    int* flag      = (int*)alloc(4);
    int* offs      = (int*)alloc((size_t)B_PART * 256 * 4);   // hist/offsets (bucket-major)
    int* sumsA     = (int*)alloc(1024 * 4);
    int* rowptr    = (int*)alloc((size_t)(n + 1) * 4);
    float* dinv    = (float*)alloc((size_t)n * 4);
    int* csr_src   = (int*)alloc((size_t)eN * 4);
    float* bufA    = (float*)alloc((size_t)n * DIM * 4);
    float* bufB    = (float*)alloc((size_t)n * DIM * 4);
    size_t pairsB  = (size_t)eN * 4;
    size_t bufCB   = (size_t)n * DIM * 4;
    void* shared0  = alloc(pairsB > bufCB ? pairsB : bufCB);  // pairs, later bufC
    unsigned int* pairs = (unsigned int*)shared0;
    float* bufC    = (float*)shared0;

    detect_dtype_kernel<<<1, 256, 0, stream>>>(edge, flag, n);
    hist_kernel<<<B_PART, 256, 0, stream>>>(edge, flag, offs, eN, NB, chunk);
    scanA_kernel<<<nbA, 512, 0, stream>>>(offs, sumsA, M);
    scanB_kernel<<<1, 1024, 0, stream>>>(sumsA, nbA);
    scanC_kernel<<<nbA, 512, 0, stream>>>(offs, sumsA, M);
    partition_kernel<<<B_PART, 256, 0, stream>>>(edge, flag, offs, pairs, eN, NB, chunk);
    bucket_fill_kernel<<<NB, 256, 0, stream>>>(pairs, offs, rowptr, dinv, csr_src, n, eN, NB);

    int ab = (n + 7) / 8;

    // Res-block 1 (residual = x): x -> bufA -> bufB
    fused_conv_kernel<0><<<ab, 256, 0, stream>>>(x,    rowptr, csr_src, dinv, W[0], B[0], nullptr, bufA, n);
    fused_conv_kernel<1><<<ab, 256, 0, stream>>>(bufA, rowptr, csr_src, dinv, W[1], B[1], x,       bufB, n);
    // Res-block 2 (residual = bufB): bufB -> bufA -> bufC  (pairs dead now)
    fused_conv_kernel<0><<<ab, 256, 0, stream>>>(bufB, rowptr, csr_src, dinv, W[2], B[2], nullptr, bufA, n);
    fused_conv_kernel<1><<<ab, 256, 0, stream>>>(bufA, rowptr, csr_src, dinv, W[3], B[3], bufB,    bufC, n);
    // Res-block 3 (residual = bufC): bufC -> bufA -> bufB
    fused_conv_kernel<0><<<ab, 256, 0, stream>>>(bufC, rowptr, csr_src, dinv, W[4], B[4], nullptr, bufA, n);
    fused_conv_kernel<1><<<ab, 256, 0, stream>>>(bufA, rowptr, csr_src, dinv, W[5], B[5], bufC,    bufB, n);

    pool_fc_kernel<<<gN, 128, 0, stream>>>(bufB, batch, flag, Wl, bl, out, n);
}

// Round 5
// 523.340 us; speedup vs baseline: 2.6021x; 1.0663x over previous
//
#include <hip/hip_runtime.h>
#include <hip/hip_bf16.h>
#include <cstdint>

#define DIM 32
#define OUTD 128
#define B_PART 256     // blocks in hist/partition passes
#define BSHIFT 9       // bucket = 512 nodes

// ---------------- bf16 helpers (RNE) ----------------
__device__ __forceinline__ unsigned short f32_to_bf16_rne(float f) {
    unsigned u = __float_as_uint(f);
    unsigned r = u + 0x7FFFu + ((u >> 16) & 1u);
    return (unsigned short)(r >> 16);
}
__device__ __forceinline__ float bf16_to_f32(unsigned short h) {
    return __uint_as_float(((unsigned)h) << 16);
}

// ---------------- index-load helper (int32 vs int64 inputs) ----------------
__device__ __forceinline__ int load_idx(const void* p, long long i, int is64) {
    if (is64) return (int)((const long long*)p)[i];
    return ((const int*)p)[i];
}

// Detect whether integer inputs are int64 (8B) or int32 (4B).
__global__ void detect_dtype_kernel(const void* __restrict__ edge, int* __restrict__ flag, int n_nodes) {
    __shared__ int cnt;
    if (threadIdx.x == 0) cnt = 0;
    __syncthreads();
    long long v = ((const long long*)edge)[threadIdx.x];
    int ok = (v >= 0 && v < (long long)n_nodes) ? 1 : 0;
    atomicAdd(&cnt, ok);
    __syncthreads();
    if (threadIdx.x == 0) *flag = (cnt > 128) ? 1 : 0;
}

// ---- pass 1: per-(bucket, block) histogram of destination buckets ----
__global__ __launch_bounds__(256) void hist_kernel(const void* __restrict__ edge,
                                                   const int* __restrict__ flag,
                                                   int* __restrict__ histT,
                                                   int eN, int NB, int chunk) {
    __shared__ int sh[256];
    int t = threadIdx.x, bid = blockIdx.x;
    sh[t] = 0;
    __syncthreads();
    int f = *flag;
    int s = bid * chunk, e = min(eN, s + chunk);
    for (int i = s + t; i < e; i += 256) {
        int c = load_idx(edge, (long long)eN + i, f);
        atomicAdd(&sh[c >> BSHIFT], 1);
    }
    __syncthreads();
    if (t < NB) histT[t * B_PART + bid] = sh[t];   // bucket-major layout
}

// ---- generic hierarchical exclusive scan over M ints (A: block sums) ----
__global__ __launch_bounds__(512) void scanA_kernel(const int* __restrict__ a,
                                                    int* __restrict__ sums, int M) {
    __shared__ int red[512];
    int i = blockIdx.x * 512 + threadIdx.x;
    int v = (i < M) ? a[i] : 0;
    red[threadIdx.x] = v;
    __syncthreads();
    for (int off = 256; off > 0; off >>= 1) {
        if (threadIdx.x < off) red[threadIdx.x] += red[threadIdx.x + off];
        __syncthreads();
    }
    if (threadIdx.x == 0) sums[blockIdx.x] = red[0];
}

// ---- B: exclusive scan of block sums (<=1024) ----
__global__ __launch_bounds__(1024) void scanB_kernel(int* __restrict__ sums, int nb) {
    __shared__ int part[1024];
    int t = threadIdx.x;
    int v = (t < nb) ? sums[t] : 0;
    part[t] = v;
    __syncthreads();
    for (int off = 1; off < 1024; off <<= 1) {
        int u = (t >= off) ? part[t - off] : 0;
        __syncthreads();
        part[t] += u;
        __syncthreads();
    }
    if (t < nb) sums[t] = part[t] - v;
}

// ---- C: apply (in-place exclusive scan) ----
__global__ __launch_bounds__(512) void scanC_kernel(int* __restrict__ a,
                                                    const int* __restrict__ sums, int M) {
    __shared__ int part[512];
    int t = threadIdx.x;
    int i = blockIdx.x * 512 + t;
    int v = (i < M) ? a[i] : 0;
    part[t] = v;
    __syncthreads();
    for (int off = 1; off < 512; off <<= 1) {
        int u = (t >= off) ? part[t - off] : 0;
        __syncthreads();
        part[t] += u;
        __syncthreads();
    }
    if (i < M) a[i] = part[t] - v + sums[blockIdx.x];
}

// ---- pass 2: partition edges into bucket runs; pack (r | local_c<<23) in 4B ----
__global__ __launch_bounds__(256) void partition_kernel(const void* __restrict__ edge,
                                                        const int* __restrict__ flag,
                                                        const int* __restrict__ offs,
                                                        unsigned int* __restrict__ pairs,
                                                        int eN, int NB, int chunk) {
    __shared__ int cur[256];
    int t = threadIdx.x, bid = blockIdx.x;
    if (t < NB) cur[t] = offs[t * B_PART + bid];
    __syncthreads();
    int f = *flag;
    int s = bid * chunk, e = min(eN, s + chunk);
    for (int i = s + t; i < e; i += 256) {
        int r = load_idx(edge, i, f);
        int c = load_idx(edge, (long long)eN + i, f);
        int slot = atomicAdd(&cur[c >> BSHIFT], 1);
        pairs[slot] = (unsigned)r | ((unsigned)(c & 511) << 23);
    }
}

// ---- pass 3: per-bucket CSR build (rowptr, dinv, csr_src) with L2-local writes ----
__global__ __launch_bounds__(256) void bucket_fill_kernel(const unsigned int* __restrict__ pairs,
                                                          const int* __restrict__ offs,
                                                          int* __restrict__ rowptr,
                                                          float* __restrict__ dinv,
                                                          int* __restrict__ csr_src,
                                                          int n, int eN, int NB) {
    __shared__ int lcnt[512];
    __shared__ int lofs[512];
    __shared__ int psum[256];
    int t = threadIdx.x, b = blockIdx.x;
    int base = b << BSHIFT;
    int nLocal = min(512, n - base);
    int s = offs[b * B_PART];
    int e = (b + 1 < NB) ? offs[(b + 1) * B_PART] : eN;
    lcnt[t] = 0;
    lcnt[t + 256] = 0;
    __syncthreads();
    for (int i = s + t; i < e; i += 256) atomicAdd(&lcnt[pairs[i] >> 23], 1);
    __syncthreads();
    int a0 = lcnt[2 * t], a1 = lcnt[2 * t + 1];
    psum[t] = a0 + a1;
    __syncthreads();
    for (int off = 1; off < 256; off <<= 1) {
        int u = (t >= off) ? psum[t - off] : 0;
        __syncthreads();
        psum[t] += u;
        __syncthreads();
    }
    int ex = psum[t] - (a0 + a1);
    lofs[2 * t] = ex;
    lofs[2 * t + 1] = ex + a0;
    __syncthreads();
    for (int j = t; j < nLocal; j += 256) {
        rowptr[base + j] = s + lofs[j];
        dinv[base + j] = rsqrtf((float)(lcnt[j] + 1));
    }
    if (b == NB - 1 && t == 0) rowptr[n] = eN;
    __syncthreads();
    lcnt[t] = lofs[t];
    lcnt[t + 256] = lofs[t + 256];
    __syncthreads();
    for (int i = s + t; i < e; i += 256) {
        unsigned p = pairs[i];
        int lc = (int)(p >> 23);
        int r = (int)(p & 0x7FFFFFu);
        int slot = atomicAdd(&lcnt[lc], 1);
        csr_src[s + slot] = r;
    }
}

// prep: sb[i] = bf16(dinv[node] * x[i])
__global__ __launch_bounds__(256) void prescale_kernel(const float* __restrict__ x,
                                                       const float* __restrict__ dinv,
                                                       unsigned short* __restrict__ sb, int total) {
    int i = blockIdx.x * 256 + threadIdx.x;
    if (i >= total) return;
    sb[i] = f32_to_bf16_rne(dinv[i >> 5] * x[i]);
}

// Fused GCN conv on pre-scaled bf16 rows:
//   agg_k = dinv_c * ( sum_e sb[src_e][k] + sb[c][k] )        (sb = bf16(dinv*h))
//   o     = relu( agg @ W + b (+ res) )
//   out f32; optional sb_out = bf16(dinv_c * o)
// 8 nodes/block, 32 lanes per node (lane = feature). W column k kept in registers.
template <int HAS_RES>
__global__ __launch_bounds__(256) void fused_conv_kernel(const unsigned short* __restrict__ sb,
                                                         const int* __restrict__ rowptr,
                                                         const int* __restrict__ src,
                                                         const float* __restrict__ dinv,
                                                         const float* __restrict__ W,
                                                         const float* __restrict__ bias,
                                                         const float* __restrict__ res,
                                                         float* __restrict__ out,
                                                         unsigned short* __restrict__ sb_out,
                                                         int n) {
    int t = threadIdx.x;
    int k = t & 31;
    float wr[32];
    #pragma unroll
    for (int j = 0; j < 32; ++j) wr[j] = W[j * 32 + k];
    float bk = bias[k];
    int g = blockIdx.x * 8 + (t >> 5);
    if (g >= n) return;
    float di = dinv[g];
    float acc = bf16_to_f32(sb[(size_t)g * 32 + k]);   // self term (pre-scaled)
    int s = rowptr[g], e = rowptr[g + 1];
    int p = s;
    for (; p + 7 < e; p += 8) {
        int sr0 = src[p];
        int sr1 = src[p + 1];
        int sr2 = src[p + 2];
        int sr3 = src[p + 3];
        int sr4 = src[p + 4];
        int sr5 = src[p + 5];
        int sr6 = src[p + 6];
        int sr7 = src[p + 7];
        float v0 = bf16_to_f32(sb[(size_t)sr0 * 32 + k]);
        float v1 = bf16_to_f32(sb[(size_t)sr1 * 32 + k]);
        float v2 = bf16_to_f32(sb[(size_t)sr2 * 32 + k]);
        float v3 = bf16_to_f32(sb[(size_t)sr3 * 32 + k]);
        float v4 = bf16_to_f32(sb[(size_t)sr4 * 32 + k]);
        float v5 = bf16_to_f32(sb[(size_t)sr5 * 32 + k]);
        float v6 = bf16_to_f32(sb[(size_t)sr6 * 32 + k]);
        float v7 = bf16_to_f32(sb[(size_t)sr7 * 32 + k]);
        acc += ((v0 + v1) + (v2 + v3)) + ((v4 + v5) + (v6 + v7));
    }
    for (; p < e; ++p) {
        int sr = src[p];
        acc += bf16_to_f32(sb[(size_t)sr * 32 + k]);
    }
    float agg = di * acc;
    float o = bk;
    #pragma unroll
    for (int j = 0; j < 32; ++j) {
        float aj = __shfl(agg, j, 32);
        o = fmaf(aj, wr[j], o);
    }
    if (HAS_RES) o += res[(size_t)g * 32 + k];
    o = fmaxf(o, 0.f);
    out[(size_t)g * 32 + k] = o;
    if (sb_out) sb_out[(size_t)g * 32 + k] = f32_to_bf16_rne(di * o);
}

// one block per graph: mean-pool (batch is sorted -> binary search range) + 32->128 FC
__global__ __launch_bounds__(128) void pool_fc_kernel(const float* __restrict__ h,
                                                      const void* __restrict__ batch,
                                                      const int* __restrict__ flag,
                                                      const float* __restrict__ Wl,
                                                      const float* __restrict__ bl,
                                                      float* __restrict__ out, int n) {
    __shared__ float red[4][32];
    __shared__ float sp[32];
    __shared__ int srange[2];
    int g = blockIdx.x;
    int t = threadIdx.x;
    int f = *flag;
    if (t < 2) {
        int target = g + t;
        int lo = 0, hi = n;
        while (lo < hi) {
            int mid = (lo + hi) >> 1;
            int v = load_idx(batch, mid, f);
            if (v < target) lo = mid + 1; else hi = mid;
        }
        srange[t] = lo;
    }
    __syncthreads();
    int s = srange[0], e = srange[1];
    int gi = t >> 5, k = t & 31;
    float acc = 0.f;
    for (int i = s + gi; i < e; i += 4) acc += h[(size_t)i * 32 + k];
    red[gi][k] = acc;
    __syncthreads();
    if (gi == 0) {
        float v = red[0][k] + red[1][k] + red[2][k] + red[3][k];
        sp[k] = v / fmaxf((float)(e - s), 1.0f);
    }
    __syncthreads();
    float val = bl[t];
    #pragma unroll
    for (int j = 0; j < 32; ++j) val = fmaf(sp[j], Wl[j * 128 + t], val);
    out[(size_t)g * 128 + t] = val;
}

extern "C" void kernel_launch(void* const* d_in, const int* in_sizes, int n_in,
                              void* d_out, int out_size, void* d_ws, size_t ws_size,
                              hipStream_t stream) {
    const float* x = (const float*)d_in[0];
    const void* edge = d_in[1];
    const void* batch = d_in[2];
    const float* W[6] = {(const float*)d_in[3], (const float*)d_in[5],
                         (const float*)d_in[7], (const float*)d_in[9],
                         (const float*)d_in[11], (const float*)d_in[13]};
    const float* B[6] = {(const float*)d_in[4], (const float*)d_in[6],
                         (const float*)d_in[8], (const float*)d_in[10],
                         (const float*)d_in[12], (const float*)d_in[14]};
    const float* Wl = (const float*)d_in[15];
    const float* bl = (const float*)d_in[16];
    float* out = (float*)d_out;

    int n = in_sizes[0] / DIM;      // 100000 nodes
    int eN = in_sizes[1] / 2;       // 3200000 edges
    int gN = out_size / OUTD;       // 8192 graphs

    int NB = (n + 511) >> BSHIFT;   // 196 buckets (<=256 for n<=131072)
    int M = NB * B_PART;            // hist matrix size
    int chunk = (eN + B_PART - 1) / B_PART;
    int nbA = (M + 511) / 512;

    char* ws = (char*)d_ws;
    size_t off = 0;
    auto alloc = [&](size_t bytes) {
        void* p = ws + off;
        off += (bytes + 255) & ~(size_t)255;
        return p;
    };
    int* flag      = (int*)alloc(4);
    int* offs      = (int*)alloc((size_t)B_PART * 256 * 4);   // hist/offsets (bucket-major)
    int* sumsA     = (int*)alloc(1024 * 4);
    int* rowptr    = (int*)alloc((size_t)(n + 1) * 4);
    float* dinv    = (float*)alloc((size_t)n * 4);
    int* csr_src   = (int*)alloc((size_t)eN * 4);
    float* bufA    = (float*)alloc((size_t)n * DIM * 4);
    float* bufB    = (float*)alloc((size_t)n * DIM * 4);
    unsigned short* sbX = (unsigned short*)alloc((size_t)n * DIM * 2);
    unsigned short* sbA = (unsigned short*)alloc((size_t)n * DIM * 2);
    unsigned short* sbB = (unsigned short*)alloc((size_t)n * DIM * 2);
    unsigned short* sbC = (unsigned short*)alloc((size_t)n * DIM * 2);
    size_t pairsB  = (size_t)eN * 4;
    size_t bufCB   = (size_t)n * DIM * 4;
    void* shared0  = alloc(pairsB > bufCB ? pairsB : bufCB);  // pairs, later bufC
    unsigned int* pairs = (unsigned int*)shared0;
    float* bufC    = (float*)shared0;

    detect_dtype_kernel<<<1, 256, 0, stream>>>(edge, flag, n);
    hist_kernel<<<B_PART, 256, 0, stream>>>(edge, flag, offs, eN, NB, chunk);
    scanA_kernel<<<nbA, 512, 0, stream>>>(offs, sumsA, M);
    scanB_kernel<<<1, 1024, 0, stream>>>(sumsA, nbA);
    scanC_kernel<<<nbA, 512, 0, stream>>>(offs, sumsA, M);
    partition_kernel<<<B_PART, 256, 0, stream>>>(edge, flag, offs, pairs, eN, NB, chunk);
    bucket_fill_kernel<<<NB, 256, 0, stream>>>(pairs, offs, rowptr, dinv, csr_src, n, eN, NB);

    int total = n * DIM;
    prescale_kernel<<<(total + 255) / 256, 256, 0, stream>>>(x, dinv, sbX, total);

    int ab = (n + 7) / 8;

    // Res-block 1: x -> bufA(+sbA) -> bufB(+sbB)
    fused_conv_kernel<0><<<ab, 256, 0, stream>>>(sbX, rowptr, csr_src, dinv, W[0], B[0], nullptr, bufA, sbA, n);
    fused_conv_kernel<1><<<ab, 256, 0, stream>>>(sbA, rowptr, csr_src, dinv, W[1], B[1], x,       bufB, sbB, n);
    // Res-block 2: bufB -> bufA(+sbA) -> bufC(+sbC)   (pairs dead now)
    fused_conv_kernel<0><<<ab, 256, 0, stream>>>(sbB, rowptr, csr_src, dinv, W[2], B[2], nullptr, bufA, sbA, n);
    fused_conv_kernel<1><<<ab, 256, 0, stream>>>(sbA, rowptr, csr_src, dinv, W[3], B[3], bufB,    bufC, sbC, n);
    // Res-block 3: bufC -> bufA(+sbA) -> bufB (final, no sb out)
    fused_conv_kernel<0><<<ab, 256, 0, stream>>>(sbC, rowptr, csr_src, dinv, W[4], B[4], nullptr, bufA, sbA, n);
    fused_conv_kernel<1><<<ab, 256, 0, stream>>>(sbA, rowptr, csr_src, dinv, W[5], B[5], bufC,    bufB, nullptr, n);

    pool_fc_kernel<<<gN, 128, 0, stream>>>(bufB, batch, flag, Wl, bl, out, n);
}